// Round 2
// baseline (341.136 us; speedup 1.0000x reference)
//
#include <hip/hip_runtime.h>
#include <hip/hip_bf16.h>
#include <math.h>

#define BB 2
#define CC 256
#define CMID 16
#define HH 96
#define WW 96
#define HWSZ (HH*WW)
#define SH 48
#define SHSZ (SH*SH)
#define MMK 7
#define HO 90
#define WO 90
#define NPATCH (HO*WO)
#define NSITE (BB*CMID*NPATCH)

typedef __hip_bfloat16 bf16;

__device__ __forceinline__ float ldf(const bf16* p){ return __bfloat162float(*p); }
__device__ __forceinline__ float ldf(const float* p){ return *p; }
__device__ __forceinline__ void stf(bf16* p, float v){ *p = __float2bfloat16(v); }
__device__ __forceinline__ void stf(float* p, float v){ *p = v; }

// ---------------- dtype detect: 1 = inputs are fp32, 0 = inputs are bf16.
// Reading fp32 gaussian data as bf16 halves: the low half's exponent field is
// fp32 mantissa bits (~uniform) -> ~0.4% decode as exp==0xFF. True bf16
// gaussian data (|v|<~7) never has exp 0xFF.
__global__ void k_detect(const unsigned short* __restrict__ bits, int* __restrict__ flag) {
    __shared__ int cnt;
    if (threadIdx.x == 0) cnt = 0;
    __syncthreads();
    int c = 0;
    for (int i = threadIdx.x; i < 65536; i += 256)
        if (((bits[i] >> 7) & 0xFF) == 0xFF) c++;
    if (c) atomicAdd(&cnt, c);
    __syncthreads();
    if (threadIdx.x == 0) *flag = (cnt > 0) ? 1 : 0;
}

// ---------------- bilinear upsample coords (exact dyadic arithmetic; bit-
// reproducible across both call sites, matching the reference's fp32 math)
struct BiC { int r0, r1; float wr; };
__device__ __forceinline__ BiC bic(int y) {
    float sy = fminf(fmaxf((y + 0.5f) * 0.5f - 0.5f, 0.f), 47.f);
    BiC b; b.r0 = (int)sy; b.r1 = min(b.r0 + 1, 47); b.wr = sy - (float)b.r0;
    return b;
}
template<typename T>
__device__ __forceinline__ float upsamp(const T* __restrict__ plane, BiC ry, BiC rx) {
    float v00 = ldf(plane + ry.r0 * SH + rx.r0);
    float v01 = ldf(plane + ry.r0 * SH + rx.r1);
    float v10 = ldf(plane + ry.r1 * SH + rx.r0);
    float v11 = ldf(plane + ry.r1 * SH + rx.r1);
    float row0 = v00 * (1.f - ry.wr) + v10 * ry.wr;   // reference order: rows first
    float row1 = v01 * (1.f - ry.wr) + v11 * ry.wr;
    return row0 * (1.f - rx.wr) + row1 * rx.wr;
}

// ---------------- K1a: xl(b,o,hw) = sum_c x_low(b,c,hw) * w_low(o,c)
template<typename T, int FLAGV>
__global__ __launch_bounds__(256) void k_proj_low(const T* __restrict__ src,
                                                  const T* __restrict__ wmat,
                                                  float* __restrict__ dst,
                                                  const int* __restrict__ flag) {
    if (*flag != FLAGV) return;
    __shared__ float wsm[CMID * CC];
    for (int t = threadIdx.x; t < CMID * CC; t += 256) wsm[t] = ldf(wmat + t);
    __syncthreads();
    int t = blockIdx.x * 256 + threadIdx.x;
    if (t >= BB * HWSZ) return;
    int b = t / HWSZ, hw = t % HWSZ;
    const T* sp = src + (size_t)b * CC * HWSZ + hw;
    float acc[CMID];
#pragma unroll
    for (int o = 0; o < CMID; o++) acc[o] = 0.f;
    for (int c = 0; c < CC; c++) {
        float v = ldf(sp + (size_t)c * HWSZ);
#pragma unroll
        for (int o = 0; o < CMID; o++) acc[o] = fmaf(v, wsm[o * CC + c], acc[o]);
    }
    float* dp = dst + (size_t)b * CMID * HWSZ + hw;
#pragma unroll
    for (int o = 0; o < CMID; o++) dp[o * HWSZ] = acc[o];
}

// ---------------- K1b: xh(b,o,hw) = sum_c upsample(x_high)(b,c,hw) * w_high(o,c)
template<typename T, int FLAGV>
__global__ __launch_bounds__(256) void k_proj_high(const T* __restrict__ xhigh,
                                                   const T* __restrict__ wmat,
                                                   float* __restrict__ dst,
                                                   const int* __restrict__ flag) {
    if (*flag != FLAGV) return;
    __shared__ float wsm[CMID * CC];
    for (int t = threadIdx.x; t < CMID * CC; t += 256) wsm[t] = ldf(wmat + t);
    __syncthreads();
    int t = blockIdx.x * 256 + threadIdx.x;
    if (t >= BB * HWSZ) return;
    int b = t / HWSZ, hw = t % HWSZ;
    int x = hw % WW, y = hw / WW;
    BiC ry = bic(y), rx = bic(x);
    const T* sp = xhigh + (size_t)b * CC * SHSZ;
    float acc[CMID];
#pragma unroll
    for (int o = 0; o < CMID; o++) acc[o] = 0.f;
    for (int c = 0; c < CC; c++) {
        float v = upsamp(sp + (size_t)c * SHSZ, ry, rx);
#pragma unroll
        for (int o = 0; o < CMID; o++) acc[o] = fmaf(v, wsm[o * CC + c], acc[o]);
    }
    float* dp = dst + (size_t)b * CMID * HWSZ + hw;
#pragma unroll
    for (int o = 0; o < CMID; o++) dp[o * HWSZ] = acc[o];
}

// ---------------- direction estimate (replicates the reference's fftshift
// indexing quirk: shifted-mag scored with unshifted rho/theta tables)
__device__ float estimate_dir(const float* __restrict__ p) {
    float pv[49];
#pragma unroll
    for (int r = 0; r < 7; r++)
#pragma unroll
        for (int c = 0; c < 7; c++) pv[r * 7 + c] = p[r * WW + c];

    constexpr float TRE[7] = {1.f, 0.6234898019f, -0.2225209340f, -0.9009688679f,
                              -0.9009688679f, -0.2225209340f, 0.6234898019f};
    constexpr float TIM[7] = {0.f, -0.7818314825f, -0.9749279122f, -0.4338837391f,
                              0.4338837391f, 0.9749279122f, 0.7818314825f};
    constexpr float FS[7] = {3.f, -3.f, -2.f, -1.f, 0.f, 1.f, 2.f}; // f[(t+3)%7]

    float best = -1.f;
    int bk = 0;
#pragma unroll
    for (int u = 0; u < 4; u++) {  // Hermitian symmetry: u=0..3 suffices
        float Ar[7], Ai[7];
#pragma unroll
        for (int c = 0; c < 7; c++) { Ar[c] = 0.f; Ai[c] = 0.f; }
#pragma unroll
        for (int r = 0; r < 7; r++) {
            const int t = (u * r) % 7;
            const float wre = TRE[t], wim = TIM[t];
#pragma unroll
            for (int c = 0; c < 7; c++) {
                float v = pv[r * 7 + c];
                Ar[c] = fmaf(v, wre, Ar[c]);
                Ai[c] = fmaf(v, wim, Ai[c]);
            }
        }
#pragma unroll
        for (int v = 0; v < 7; v++) {
            if (u == 0 && v >= 4) continue;  // row-0 conjugates live within the row
            float Fr = 0.f, Fi = 0.f;
#pragma unroll
            for (int c = 0; c < 7; c++) {
                const int t = (v * c) % 7;
                Fr += Ar[c] * TRE[t] - Ai[c] * TIM[t];
                Fi += Ar[c] * TIM[t] + Ai[c] * TRE[t];
            }
            float mag = sqrtf(Fr * Fr + Fi * Fi) * (1.f / 7.f) + 1e-8f;
            {
                const int k1 = ((u + 3) % 7) * 7 + ((v + 3) % 7);
                if (k1 != 0) {
                    float s = mag * sqrtf(FS[u] * FS[u] + FS[v] * FS[v]);
                    if (s > best || (s == best && k1 < bk)) { best = s; bk = k1; }
                }
            }
            const int u2 = (7 - u) % 7, v2 = (7 - v) % 7;
            if (u2 != u || v2 != v) {  // conjugate: same mag, different rho/k
                const int k2 = ((u2 + 3) % 7) * 7 + ((v2 + 3) % 7);
                if (k2 != 0) {
                    float s = mag * sqrtf(FS[u2] * FS[u2] + FS[v2] * FS[v2]);
                    if (s > best || (s == best && k2 < bk)) { best = s; bk = k2; }
                }
            }
        }
    }
    int bi = bk / 7, bj = bk % 7;
    float fi = (float)(bi <= 3 ? bi : bi - 7);
    float fj = (float)(bj <= 3 ? bj : bj - 7);
    float th = atan2f(fi, fj);
    if (th < 0.f) th += 6.28318530717958647692f;
    const float PI_F = 3.14159265358979323846f;
    if (th >= PI_F) th -= PI_F;
    return th;
}

// ---------------- K2: per-site rotation angle -> cos/sin (dtype-independent)
__global__ __launch_bounds__(256) void k_theta(const float* __restrict__ xl,
                                               const float* __restrict__ xh,
                                               float* __restrict__ cosd,
                                               float* __restrict__ sind) {
    int s = blockIdx.x * 256 + threadIdx.x;
    if (s >= NSITE) return;
    int n = s % NPATCH;
    int bcm = s / NPATCH;
    int py = n / WO, px = n % WO;
    size_t off = (size_t)bcm * HWSZ + py * WW + px;
    float tl = estimate_dir(xl + off);
    float th = estimate_dir(xh + off);
    float d = tl - th;
    cosd[s] = cosf(d);
    sind[s] = sinf(d);
}

// ---------------- K3: gather-fold rotated patches -> aligned (dtype-independent)
__global__ __launch_bounds__(256) void k_fold(const float* __restrict__ xh,
                                              const float* __restrict__ cosd,
                                              const float* __restrict__ sind,
                                              float* __restrict__ alg) {
    int idx = blockIdx.x * 256 + threadIdx.x;
    if (idx >= BB * CMID * HWSZ) return;
    int x = idx % WW;
    int y = (idx / WW) % HH;
    int bcm = idx / HWSZ;
    const float* hp = xh + (size_t)bcm * HWSZ;
    const float* cb = cosd + (size_t)bcm * NPATCH;
    const float* sb = sind + (size_t)bcm * NPATCH;
    float acc = 0.f;
    int ilo = max(0, y - (HO - 1)), ihi = min(MMK - 1, y);
    int jlo = max(0, x - (WO - 1)), jhi = min(MMK - 1, x);
    for (int i = ilo; i <= ihi; i++) {
        int py = y - i;
        float by = -1.f + (2.f * i + 1.f) / 7.f;
        for (int j = jlo; j <= jhi; j++) {
            int px = x - j;
            int n = py * WO + px;
            float cs = cb[n], sn = sb[n];
            float tx = 3.f - cs * 3.f + sn * 3.f;
            float ty = 3.f - sn * 3.f - cs * 3.f;
            float bx = -1.f + (2.f * j + 1.f) / 7.f;
            float gx = cs * bx - sn * by + tx;
            float gy = sn * bx + cs * by + ty;
            float ix = ((gx + 1.f) * 7.f - 1.f) * 0.5f;
            float iy = ((gy + 1.f) * 7.f - 1.f) * 0.5f;
            float x0 = floorf(ix), y0 = floorf(iy);
#pragma unroll
            for (int dy = 0; dy < 2; dy++)
#pragma unroll
                for (int dx = 0; dx < 2; dx++) {
                    float xc = x0 + dx, yc = y0 + dy;
                    if (xc >= 0.f && xc <= 6.f && yc >= 0.f && yc <= 6.f) {
                        float wgt = (1.f - fabsf(ix - xc)) * (1.f - fabsf(iy - yc));
                        acc = fmaf(hp[(py + (int)yc) * WW + (px + (int)xc)], wgt, acc);
                    }
                }
        }
    }
    float cy = fminf(fminf((float)(y + 1), 7.f), fminf((float)(HH - y), (float)(HH - MMK + 1)));
    float cx = fminf(fminf((float)(x + 1), 7.f), fminf((float)(WW - x), (float)(WW - MMK + 1)));
    alg[idx] = acc / (cy * cx + 1e-8f);
}

// ---------------- K4: out = x_low + ls * (w_recon . aligned) + upsample(x_high)
template<typename T, typename OT, int FLAGV>
__global__ __launch_bounds__(256) void k_final(const T* __restrict__ x_low,
                                               const T* __restrict__ x_high,
                                               const float* __restrict__ alg,
                                               const T* __restrict__ wrec,
                                               const T* __restrict__ lscale,
                                               OT* __restrict__ out,
                                               const int* __restrict__ flag) {
    if (*flag != FLAGV) return;
    int idx = blockIdx.x * 256 + threadIdx.x;
    if (idx >= BB * CC * HWSZ) return;
    int hw = idx % HWSZ;
    int c = (idx / HWSZ) % CC;
    int b = idx / (CC * HWSZ);
    int x = hw % WW, y = hw / WW;
    const float* ap = alg + (size_t)b * CMID * HWSZ + hw;
    float rec = 0.f;
#pragma unroll
    for (int o = 0; o < CMID; o++)
        rec = fmaf(ap[o * HWSZ], ldf(wrec + c * CMID + o), rec);
    float upv = upsamp(x_high + ((size_t)b * CC + c) * SHSZ, bic(y), bic(x));
    float ls = ldf(lscale);
    float v = ldf(x_low + idx) + ls * rec;   // reference order: (x_low + ls*rec) + up
    stf(out + idx, v + upv);
}

extern "C" void kernel_launch(void* const* d_in, const int* in_sizes, int n_in,
                              void* d_out, int out_size, void* d_ws, size_t ws_size,
                              hipStream_t stream) {
    int* flag = (int*)d_ws;
    float* base = (float*)d_ws + 4;                 // 16-byte offset
    float* xl   = base;                             // 294,912 f
    float* xh   = xl + (size_t)BB * CMID * HWSZ;    // 294,912 f
    float* cosd = xh + (size_t)BB * CMID * HWSZ;    // 259,200 f
    float* sind = cosd + NSITE;                     // 259,200 f
    float* alg  = sind + NSITE;                     // 294,912 f   (total ~5.6 MB)

    k_detect<<<1, 256, 0, stream>>>((const unsigned short*)d_in[0], flag);

    const int gp = (BB * HWSZ + 255) / 256;
    const int gf = (BB * CC * HWSZ + 255) / 256;

    // bf16-input variant (flag==0)
    k_proj_low<bf16, 0><<<gp, 256, 0, stream>>>((const bf16*)d_in[1], (const bf16*)d_in[2], xl, flag);
    k_proj_high<bf16, 0><<<gp, 256, 0, stream>>>((const bf16*)d_in[0], (const bf16*)d_in[3], xh, flag);
    // fp32-input variant (flag==1)
    k_proj_low<float, 1><<<gp, 256, 0, stream>>>((const float*)d_in[1], (const float*)d_in[2], xl, flag);
    k_proj_high<float, 1><<<gp, 256, 0, stream>>>((const float*)d_in[0], (const float*)d_in[3], xh, flag);

    k_theta<<<(NSITE + 255) / 256, 256, 0, stream>>>(xl, xh, cosd, sind);
    k_fold<<<(BB * CMID * HWSZ + 255) / 256, 256, 0, stream>>>(xh, cosd, sind, alg);

    k_final<bf16, bf16, 0><<<gf, 256, 0, stream>>>((const bf16*)d_in[1], (const bf16*)d_in[0], alg,
                                                   (const bf16*)d_in[4], (const bf16*)d_in[5],
                                                   (bf16*)d_out, flag);
    k_final<float, float, 1><<<gf, 256, 0, stream>>>((const float*)d_in[1], (const float*)d_in[0], alg,
                                                     (const float*)d_in[4], (const float*)d_in[5],
                                                     (float*)d_out, flag);
}